// Round 4
// baseline (6970.416 us; speedup 1.0000x reference)
//
#include <hip/hip_runtime.h>
#include <stdint.h>

#define NB 128
#define NT 2048
#define NI 128
#define NH 1024
#define NO 128

typedef float f32x4 __attribute__((ext_vector_type(4)));

// ---------------------------------------------------------------------------
// W2P: pair-transpose W2 [O][H] -> W2P [H][64] of float2 {W2[j][k], W2[j+64][k]}
// ---------------------------------------------------------------------------
__global__ __launch_bounds__(256) void w2p_kernel(
    const float* __restrict__ W2, float2* __restrict__ W2P)
{
    const int idx = blockIdx.x * 256 + threadIdx.x;  // 0..65535
    const int k = idx >> 6;                          // 0..1023
    const int j = idx & 63;                          // 0..63
    W2P[idx] = make_float2(W2[(size_t)j * NH + k], W2[(size_t)(j + 64) * NH + k]);
}

// --- phase A asm helpers ---------------------------------------------------
// W row load: per-lane 64-bit base in VGPR pair, literal byte offset.
#define WL(I, OFF)                                                        \
    asm volatile("global_load_dwordx4 %0, %1, off offset:" #OFF          \
                 : "=v"(w[I]) : "v"(wp))

// x chunk load: zero VGPR voffset + wave-uniform SGPR base + literal offset.
#define XL(DST, BASE, OFF)                                                \
    asm volatile("global_load_dwordx4 %0, %1, %2 offset:" #OFF           \
                 : "=v"(DST) : "v"(voff0), "s"(BASE))

// Wait until the oldest outstanding chunk (4 loads) completed: after each
// phase's issue there are exactly 12 newer loads in flight. Tie the buffer
// regs so no FMA can be hoisted above the wait (guide rule #18).
#define XW(BUF)                                                           \
    do {                                                                  \
        asm volatile("s_waitcnt vmcnt(12)"                                \
                     : "+v"(BUF[0]), "+v"(BUF[1]), "+v"(BUF[2]),          \
                       "+v"(BUF[3]));                                     \
        __builtin_amdgcn_sched_barrier(0);                                \
    } while (0)

#define XF(BUF, WI)                                                       \
    do {                                                                  \
        a0 = fmaf(BUF[0].x, w[WI + 0].x, a0);                             \
        a1 = fmaf(BUF[0].y, w[WI + 0].y, a1);                             \
        a2 = fmaf(BUF[0].z, w[WI + 0].z, a2);                             \
        a3 = fmaf(BUF[0].w, w[WI + 0].w, a3);                             \
        a0 = fmaf(BUF[1].x, w[WI + 1].x, a0);                             \
        a1 = fmaf(BUF[1].y, w[WI + 1].y, a1);                             \
        a2 = fmaf(BUF[1].z, w[WI + 1].z, a2);                             \
        a3 = fmaf(BUF[1].w, w[WI + 1].w, a3);                             \
        a0 = fmaf(BUF[2].x, w[WI + 2].x, a0);                             \
        a1 = fmaf(BUF[2].y, w[WI + 2].y, a1);                             \
        a2 = fmaf(BUF[2].z, w[WI + 2].z, a2);                             \
        a3 = fmaf(BUF[2].w, w[WI + 2].w, a3);                             \
        a0 = fmaf(BUF[3].x, w[WI + 3].x, a0);                             \
        a1 = fmaf(BUF[3].y, w[WI + 3].y, a1);                             \
        a2 = fmaf(BUF[3].z, w[WI + 3].z, a2);                             \
        a3 = fmaf(BUF[3].w, w[WI + 3].w, a3);                             \
    } while (0)

// ---------------------------------------------------------------------------
// Phase A: fused GEMM1 + LIF1. grid = 256 (128 b x 2 htiles of 512 h),
// block = 512 = 8 waves = exactly 1 block/CU at 2 waves/SIMD.
// Lane owns one h: W1 row (32 f32x4) pinned via asm; x row streamed through
// 4 ping-pong chunk buffers (16 floats each), 3 chunks in flight, counted
// vmcnt(12) waits. All in-loop VMEM is inline asm -> no compiler waitcnts.
// ---------------------------------------------------------------------------
__global__ __launch_bounds__(512, 2) void snn_phaseA(
    const float* __restrict__ x, const float* __restrict__ W1,
    const float* __restrict__ b1, uint64_t* __restrict__ s1bits)
{
    const int b = blockIdx.x >> 1;
    const int htile = blockIdx.x & 1;
    const int wv = threadIdx.x >> 6;
    const int lane = threadIdx.x & 63;
    const int h = (htile << 9) | (wv << 6) | lane;

    f32x4 w[32];
    const float* wp = W1 + (size_t)h * NI;
    WL(0, 0);    WL(1, 16);   WL(2, 32);   WL(3, 48);
    WL(4, 64);   WL(5, 80);   WL(6, 96);   WL(7, 112);
    WL(8, 128);  WL(9, 144);  WL(10, 160); WL(11, 176);
    WL(12, 192); WL(13, 208); WL(14, 224); WL(15, 240);
    WL(16, 256); WL(17, 272); WL(18, 288); WL(19, 304);
    WL(20, 320); WL(21, 336); WL(22, 352); WL(23, 368);
    WL(24, 384); WL(25, 400); WL(26, 416); WL(27, 432);
    WL(28, 448); WL(29, 464); WL(30, 480); WL(31, 496);
    asm volatile("s_waitcnt vmcnt(0)"
                 : "+v"(w[0]), "+v"(w[1]), "+v"(w[2]), "+v"(w[3]),
                   "+v"(w[4]), "+v"(w[5]), "+v"(w[6]), "+v"(w[7]),
                   "+v"(w[8]), "+v"(w[9]), "+v"(w[10]), "+v"(w[11]),
                   "+v"(w[12]), "+v"(w[13]), "+v"(w[14]), "+v"(w[15]),
                   "+v"(w[16]), "+v"(w[17]), "+v"(w[18]), "+v"(w[19]),
                   "+v"(w[20]), "+v"(w[21]), "+v"(w[22]), "+v"(w[23]),
                   "+v"(w[24]), "+v"(w[25]), "+v"(w[26]), "+v"(w[27]),
                   "+v"(w[28]), "+v"(w[29]), "+v"(w[30]), "+v"(w[31])
                 :
                 : "memory");
    __builtin_amdgcn_sched_barrier(0);

    float bias = b1[h];
    asm volatile("" : "+v"(bias));  // force materialization before the loop

    const float* xcur = x + (size_t)b * NT * NI;  // wave-uniform -> SGPR pair
    int voff0 = 0;
    f32x4 xq[4][4];

    // prologue: chunks 0,1,2 of row 0 (12 loads in flight)
    XL(xq[0][0], xcur, 0);   XL(xq[0][1], xcur, 16);
    XL(xq[0][2], xcur, 32);  XL(xq[0][3], xcur, 48);
    XL(xq[1][0], xcur, 64);  XL(xq[1][1], xcur, 80);
    XL(xq[1][2], xcur, 96);  XL(xq[1][3], xcur, 112);
    XL(xq[2][0], xcur, 128); XL(xq[2][1], xcur, 144);
    XL(xq[2][2], xcur, 160); XL(xq[2][3], xcur, 176);

    uint64_t* s1a = s1bits + (size_t)b * (NH / 64) + (htile << 3) + wv;

    float v = 0.0f;
#pragma unroll 1
    for (int t = 0; t < NT; ++t) {
        const float* xpf = (t < NT - 1) ? (xcur + NI) : xcur;  // uniform select
        float a0 = 0.f, a1 = 0.f, a2 = 0.f, a3 = 0.f;
        // phase 0: issue C3, consume C0
        XL(xq[3][0], xcur, 192); XL(xq[3][1], xcur, 208);
        XL(xq[3][2], xcur, 224); XL(xq[3][3], xcur, 240);
        XW(xq[0]); XF(xq[0], 0);
        // phase 1: issue C4, consume C1
        XL(xq[0][0], xcur, 256); XL(xq[0][1], xcur, 272);
        XL(xq[0][2], xcur, 288); XL(xq[0][3], xcur, 304);
        XW(xq[1]); XF(xq[1], 4);
        // phase 2: issue C5, consume C2
        XL(xq[1][0], xcur, 320); XL(xq[1][1], xcur, 336);
        XL(xq[1][2], xcur, 352); XL(xq[1][3], xcur, 368);
        XW(xq[2]); XF(xq[2], 8);
        // phase 3: issue C6, consume C3
        XL(xq[2][0], xcur, 384); XL(xq[2][1], xcur, 400);
        XL(xq[2][2], xcur, 416); XL(xq[2][3], xcur, 432);
        XW(xq[3]); XF(xq[3], 12);
        // phase 4: issue C7, consume C4
        XL(xq[3][0], xcur, 448); XL(xq[3][1], xcur, 464);
        XL(xq[3][2], xcur, 480); XL(xq[3][3], xcur, 496);
        XW(xq[0]); XF(xq[0], 16);
        // phase 5: issue next-row C0, consume C5
        XL(xq[0][0], xpf, 0);  XL(xq[0][1], xpf, 16);
        XL(xq[0][2], xpf, 32); XL(xq[0][3], xpf, 48);
        XW(xq[1]); XF(xq[1], 20);
        // phase 6: issue next-row C1, consume C6
        XL(xq[1][0], xpf, 64);  XL(xq[1][1], xpf, 80);
        XL(xq[1][2], xpf, 96);  XL(xq[1][3], xpf, 112);
        XW(xq[2]); XF(xq[2], 24);
        // phase 7: issue next-row C2, consume C7
        XL(xq[2][0], xpf, 128); XL(xq[2][1], xpf, 144);
        XL(xq[2][2], xpf, 160); XL(xq[2][3], xpf, 176);
        XW(xq[3]); XF(xq[3], 28);

        const float h1 = ((a0 + a1) + (a2 + a3)) + bias;
        v = fmaf(h1 - v, 0.5f, v);  // v += (h1 - v)/tau, tau = 2
        const bool sp = (v >= 1.0f);
        v = sp ? 0.0f : v;
        const unsigned long long mball = __ballot(sp);
        if (lane == 0)
            asm volatile("global_store_dwordx2 %0, %1, off"
                         :: "v"(s1a), "v"(mball) : "memory");
        s1a += NB * (NH / 64);
        xcur += NI;
    }
}

// ---------------------------------------------------------------------------
// Phase B: sparse GEMM2 (unchanged from R2). One wave per m row; per active
// spike one coalesced dwordx2 of W2P[k]. Sparse sum == dense sum exactly.
// ---------------------------------------------------------------------------
__global__ __launch_bounds__(256, 4) void snn_phaseB(
    const uint64_t* __restrict__ s1bits, const float2* __restrict__ W2P,
    float* __restrict__ h2)
{
    const int wv = threadIdx.x >> 6;
    const int lane = threadIdx.x & 63;
    const size_t m = (size_t)blockIdx.x * 4 + wv;  // 0..262143

    const uint64_t* __restrict__ sb = s1bits + m * (NH / 64);
    float a0 = 0.f, a1 = 0.f;

#pragma unroll 1
    for (int wd = 0; wd < NH / 64; ++wd) {
        const uint64_t m64 = sb[wd];
        const uint32_t mlo = (uint32_t)__builtin_amdgcn_readfirstlane((int)(uint32_t)m64);
        const uint32_t mhi = (uint32_t)__builtin_amdgcn_readfirstlane((int)(uint32_t)(m64 >> 32));
        uint64_t msk = ((uint64_t)mhi << 32) | mlo;
        while (msk) {
            const int i = __builtin_ctzll(msk);
            msk &= (msk - 1);
            const size_t k = ((size_t)wd << 6) + i;
            const float2 ww = W2P[k * 64 + lane];
            a0 += ww.x;
            a1 += ww.y;
        }
    }
    h2[m * NO + lane] = a0;
    h2[m * NO + 64 + lane] = a1;
}

// ---------------------------------------------------------------------------
// Phase D: LIF2 scan + decision-window count. 256 blocks of 64 threads
// (1 wave/CU across all 256 CUs), unroll 16 for 16 loads in flight.
// ---------------------------------------------------------------------------
__global__ __launch_bounds__(64) void snn_phaseD(
    const float* __restrict__ h2, const float* __restrict__ b2,
    float* __restrict__ out)
{
    const int idx = blockIdx.x * 64 + threadIdx.x;  // 0..16383
    const int b = idx >> 7;
    const int o = idx & 127;
    const float bias = b2[o];

    const float* __restrict__ p = h2 + (size_t)b * NO + o;
    float v = 0.f, c = 0.f;
#pragma unroll 16
    for (int t = 0; t < NT; ++t) {
        const float hh = p[(size_t)t * NB * NO] + bias;
        v = fmaf(hh - v, 0.5f, v);
        const bool s = (v >= 1.0f);
        v = s ? 0.f : v;
        if (t >= NT / 2) c += s ? 1.f : 0.f;
    }
    out[idx] = c;
}

extern "C" void kernel_launch(void* const* d_in, const int* in_sizes, int n_in,
                              void* d_out, int out_size, void* d_ws,
                              size_t ws_size, hipStream_t stream)
{
    const float* x  = (const float*)d_in[0];
    const float* W1 = (const float*)d_in[1];
    const float* b1 = (const float*)d_in[2];
    const float* W2 = (const float*)d_in[3];
    const float* b2 = (const float*)d_in[4];
    float* out = (float*)d_out;

    // ws layout: [s1bits 33.55 MB][W2P 0.52 MB][h2 134.2 MB]
    uint8_t* ws = (uint8_t*)d_ws;
    uint64_t* s1bits = (uint64_t*)ws;
    float2* W2P = (float2*)(ws + (size_t)NT * NB * (NH / 64) * 8);
    float* h2 = (float*)(ws + (size_t)NT * NB * (NH / 64) * 8 +
                         (size_t)NH * 64 * sizeof(float2));

    w2p_kernel<<<dim3((NH * 64) / 256), dim3(256), 0, stream>>>(W2, W2P);
    snn_phaseA<<<dim3(NB * 2), dim3(512), 0, stream>>>(x, W1, b1, s1bits);
    snn_phaseB<<<dim3((NT * NB) / 4), dim3(256), 0, stream>>>(s1bits, W2P, h2);
    snn_phaseD<<<dim3(256), dim3(64), 0, stream>>>(h2, b2, out);
}

// Round 5
// 5201.054 us; speedup vs baseline: 1.3402x; 1.3402x over previous
//
#include <hip/hip_runtime.h>
#include <stdint.h>

#define NB 128
#define NT 2048
#define NI 128
#define NH 1024
#define NO 128

typedef float f32x4 __attribute__((ext_vector_type(4)));

// ---------------------------------------------------------------------------
// W2P: pair-transpose W2 [O][H] -> W2P [H][64] of float2 {W2[j][k], W2[j+64][k]}
// ---------------------------------------------------------------------------
__global__ __launch_bounds__(256) void w2p_kernel(
    const float* __restrict__ W2, float2* __restrict__ W2P)
{
    const int idx = blockIdx.x * 256 + threadIdx.x;  // 0..65535
    const int k = idx >> 6;                          // 0..1023
    const int j = idx & 63;                          // 0..63
    W2P[idx] = make_float2(W2[(size_t)j * NH + k], W2[(size_t)(j + 64) * NH + k]);
}

// ---------------------------------------------------------------------------
// Phase A: fused GEMM1 + LIF1, weights in LDS, 4-t register blocking.
// grid = 512 (64 b-pairs x 8 htiles of 128 h), block = 256 = 4 waves:
//   wave (bloc = wv>>1, hhalf = wv&1); lane owns h = htile*128 + hhalf*64 + lane.
// W1 tile [128h][128k] = 64 KB LDS, XOR-swizzled 16B cols (col ^ (h&31)).
// Per k-quad: 1 ds_read_b128 (weights) feeds 16 FMA across 4 t's; x is
// wave-uniform -> s_load + SGPR-operand FMA. No in-loop barriers.
// ---------------------------------------------------------------------------
__global__ __launch_bounds__(256, 2) void snn_phaseA(
    const float* __restrict__ x, const float* __restrict__ W1,
    const float* __restrict__ b1, uint64_t* __restrict__ s1bits)
{
    const int bgrp = blockIdx.x >> 3;   // 0..63
    const int htile = blockIdx.x & 7;   // 0..7
    const int tid = threadIdx.x;
    const int wv = tid >> 6;
    const int lane = tid & 63;
    const int bloc = __builtin_amdgcn_readfirstlane(wv >> 1);   // 0/1
    const int hhalf = __builtin_amdgcn_readfirstlane(wv & 1);   // 0/1
    const int b = bgrp * 2 + bloc;
    const int hl = hhalf * 64 + lane;   // 0..127 within tile
    const int h = htile * 128 + hl;

    __shared__ f32x4 wlds[128 * 32];    // 64 KB, [h][col^ (h&31)]

    // Stage W1 tile: 4096 16B cols, 16 per thread; coalesced global reads,
    // conflict-free swizzled LDS writes.
#pragma unroll
    for (int i = 0; i < 16; ++i) {
        const int idx = tid + i * 256;          // 0..4095
        const int hh = idx >> 5;                // 0..127
        const int c = idx & 31;                 // 16B col
        wlds[hh * 32 + (c ^ (hh & 31))] =
            *reinterpret_cast<const f32x4*>(
                W1 + ((size_t)(htile * 128 + hh)) * NI + c * 4);
    }
    __syncthreads();

    const float bias = b1[h];
    const f32x4* __restrict__ wrow = wlds + hl * 32;
    const int swz = hl & 31;

    // wave-uniform x base (bloc readfirstlane'd) -> scalar loads
    const float* __restrict__ xb = x + (size_t)b * NT * NI;

    float v = 0.0f;
#pragma unroll 1
    for (int tc = 0; tc < NT; tc += 4) {
        const float* __restrict__ xr = xb + (size_t)tc * NI;
        float a0 = 0.f, a1 = 0.f, a2 = 0.f, a3 = 0.f;
#pragma unroll
        for (int k4 = 0; k4 < 32; ++k4) {
            const f32x4 wq = wrow[k4 ^ swz];
            const f32x4 x0 = *reinterpret_cast<const f32x4*>(xr + 0 * NI + k4 * 4);
            const f32x4 x1 = *reinterpret_cast<const f32x4*>(xr + 1 * NI + k4 * 4);
            const f32x4 x2 = *reinterpret_cast<const f32x4*>(xr + 2 * NI + k4 * 4);
            const f32x4 x3 = *reinterpret_cast<const f32x4*>(xr + 3 * NI + k4 * 4);
            a0 = fmaf(x0.x, wq.x, a0); a0 = fmaf(x0.y, wq.y, a0);
            a0 = fmaf(x0.z, wq.z, a0); a0 = fmaf(x0.w, wq.w, a0);
            a1 = fmaf(x1.x, wq.x, a1); a1 = fmaf(x1.y, wq.y, a1);
            a1 = fmaf(x1.z, wq.z, a1); a1 = fmaf(x1.w, wq.w, a1);
            a2 = fmaf(x2.x, wq.x, a2); a2 = fmaf(x2.y, wq.y, a2);
            a2 = fmaf(x2.z, wq.z, a2); a2 = fmaf(x2.w, wq.w, a2);
            a3 = fmaf(x3.x, wq.x, a3); a3 = fmaf(x3.y, wq.y, a3);
            a3 = fmaf(x3.z, wq.z, a3); a3 = fmaf(x3.w, wq.w, a3);
        }
        // LIF for the 4 t's of this chunk (sequential, exact fp32 ops)
        uint64_t* __restrict__ s1w =
            s1bits + ((size_t)tc * NB + b) * (NH / 64) + htile * 2 + hhalf;
#pragma unroll
        for (int tt = 0; tt < 4; ++tt) {
            const float acc = (tt == 0) ? a0 : (tt == 1) ? a1 : (tt == 2) ? a2 : a3;
            const float h1 = acc + bias;
            v = fmaf(h1 - v, 0.5f, v);      // v += (h1 - v)/tau, tau = 2
            const bool sp = (v >= 1.0f);
            v = sp ? 0.0f : v;
            const unsigned long long m = __ballot(sp);
            if (lane == 0) *s1w = (uint64_t)m;
            s1w += NB * (NH / 64);
        }
    }
}

// ---------------------------------------------------------------------------
// Phase B: sparse GEMM2. One wave per m = t*128+b row; lane covers o = lane
// and o+64. Scalar ff1 loop over 16 mask words; per active k one coalesced
// dwordx2 of W2P[k]. Sparse sum (ascending k) == dense sum exactly.
// ---------------------------------------------------------------------------
__global__ __launch_bounds__(256, 4) void snn_phaseB(
    const uint64_t* __restrict__ s1bits, const float2* __restrict__ W2P,
    float* __restrict__ h2)
{
    const int wv = threadIdx.x >> 6;
    const int lane = threadIdx.x & 63;
    const size_t m = (size_t)blockIdx.x * 4 + wv;  // 0..262143

    const uint64_t* __restrict__ sb = s1bits + m * (NH / 64);
    float a0 = 0.f, a1 = 0.f;

#pragma unroll 1
    for (int wd = 0; wd < NH / 64; ++wd) {
        const uint64_t m64 = sb[wd];
        const uint32_t mlo = (uint32_t)__builtin_amdgcn_readfirstlane((int)(uint32_t)m64);
        const uint32_t mhi = (uint32_t)__builtin_amdgcn_readfirstlane((int)(uint32_t)(m64 >> 32));
        uint64_t msk = ((uint64_t)mhi << 32) | mlo;
        while (msk) {
            const int i = __builtin_ctzll(msk);
            msk &= (msk - 1);
            const size_t k = ((size_t)wd << 6) + i;
            const float2 ww = W2P[k * 64 + lane];
            a0 += ww.x;
            a1 += ww.y;
        }
    }
    h2[m * NO + lane] = a0;
    h2[m * NO + 64 + lane] = a1;
}

// ---------------------------------------------------------------------------
// Phase D: LIF2 scan + decision-window count. 256 blocks of 64 threads,
// unroll 16 for deep load pipelining; lanes <-> consecutive o (coalesced).
// ---------------------------------------------------------------------------
__global__ __launch_bounds__(64) void snn_phaseD(
    const float* __restrict__ h2, const float* __restrict__ b2,
    float* __restrict__ out)
{
    const int idx = blockIdx.x * 64 + threadIdx.x;  // 0..16383
    const int b = idx >> 7;
    const int o = idx & 127;
    const float bias = b2[o];

    const float* __restrict__ p = h2 + (size_t)b * NO + o;
    float v = 0.f, c = 0.f;
#pragma unroll 16
    for (int t = 0; t < NT; ++t) {
        const float hh = p[(size_t)t * NB * NO] + bias;
        v = fmaf(hh - v, 0.5f, v);
        const bool s = (v >= 1.0f);
        v = s ? 0.f : v;
        if (t >= NT / 2) c += s ? 1.f : 0.f;
    }
    out[idx] = c;
}

extern "C" void kernel_launch(void* const* d_in, const int* in_sizes, int n_in,
                              void* d_out, int out_size, void* d_ws,
                              size_t ws_size, hipStream_t stream)
{
    const float* x  = (const float*)d_in[0];
    const float* W1 = (const float*)d_in[1];
    const float* b1 = (const float*)d_in[2];
    const float* W2 = (const float*)d_in[3];
    const float* b2 = (const float*)d_in[4];
    float* out = (float*)d_out;

    // ws layout: [s1bits 33.55 MB][W2P 0.52 MB][h2 134.2 MB]
    uint8_t* ws = (uint8_t*)d_ws;
    uint64_t* s1bits = (uint64_t*)ws;
    float2* W2P = (float2*)(ws + (size_t)NT * NB * (NH / 64) * 8);
    float* h2 = (float*)(ws + (size_t)NT * NB * (NH / 64) * 8 +
                         (size_t)NH * 64 * sizeof(float2));

    w2p_kernel<<<dim3((NH * 64) / 256), dim3(256), 0, stream>>>(W2, W2P);
    snn_phaseA<<<dim3(512), dim3(256), 0, stream>>>(x, W1, b1, s1bits);
    snn_phaseB<<<dim3((NT * NB) / 4), dim3(256), 0, stream>>>(s1bits, W2P, h2);
    snn_phaseD<<<dim3(256), dim3(64), 0, stream>>>(h2, b2, out);
}

// Round 6
// 2077.532 us; speedup vs baseline: 3.3551x; 2.5035x over previous
//
#include <hip/hip_runtime.h>
#include <stdint.h>

#define NB 128
#define NT 2048
#define NI 128
#define NH 1024
#define NO 128

typedef float f32x4 __attribute__((ext_vector_type(4)));
typedef float f32x16 __attribute__((ext_vector_type(16)));

// ---------------------------------------------------------------------------
// W2P: pair-transpose W2 [O][H] -> W2P [H][64] of float2 {W2[j][k], W2[j+64][k]}
// ---------------------------------------------------------------------------
__global__ __launch_bounds__(256) void w2p_kernel(
    const float* __restrict__ W2, float2* __restrict__ W2P)
{
    const int idx = blockIdx.x * 256 + threadIdx.x;  // 0..65535
    const int k = idx >> 6;                          // 0..1023
    const int j = idx & 63;                          // 0..63
    W2P[idx] = make_float2(W2[(size_t)j * NH + k], W2[(size_t)(j + 64) * NH + k]);
}

// Pin one weight quad in VGPRs (asm defs cannot be rematerialized).
#define WL(I, OFF)                                                        \
    asm volatile("global_load_dwordx4 %0, %1, off offset:" #OFF          \
                 : "=v"(w[I]) : "v"(wp))

// 16 FMAs: weight quads w[I0..I0+3] (k = 4*I0 .. 4*I0+15 within the k-half)
// against one 16-float SGPR x vector. Grouping: a_j accumulates k % 4 == j
// (same order as R1/R2/R4 -> absmax stayed 0.0).
#define XF4(XV, I0)                                                       \
    do {                                                                  \
        a0 = fmaf(w[I0 + 0].x, XV[0],  a0);                               \
        a1 = fmaf(w[I0 + 0].y, XV[1],  a1);                               \
        a2 = fmaf(w[I0 + 0].z, XV[2],  a2);                               \
        a3 = fmaf(w[I0 + 0].w, XV[3],  a3);                               \
        a0 = fmaf(w[I0 + 1].x, XV[4],  a0);                               \
        a1 = fmaf(w[I0 + 1].y, XV[5],  a1);                               \
        a2 = fmaf(w[I0 + 1].z, XV[6],  a2);                               \
        a3 = fmaf(w[I0 + 1].w, XV[7],  a3);                               \
        a0 = fmaf(w[I0 + 2].x, XV[8],  a0);                               \
        a1 = fmaf(w[I0 + 2].y, XV[9],  a1);                               \
        a2 = fmaf(w[I0 + 2].z, XV[10], a2);                               \
        a3 = fmaf(w[I0 + 2].w, XV[11], a3);                               \
        a0 = fmaf(w[I0 + 3].x, XV[12], a0);                               \
        a1 = fmaf(w[I0 + 3].y, XV[13], a1);                               \
        a2 = fmaf(w[I0 + 3].z, XV[14], a2);                               \
        a3 = fmaf(w[I0 + 3].w, XV[15], a3);                               \
    } while (0)

// ---------------------------------------------------------------------------
// Phase A: fused GEMM1 + LIF1.
// grid = 1024 (128 b x 8 htiles of 128 h), block = 256 = 4 waves:
//   wave wv -> (khalf = wv>>1, hhalf = wv&1); lane owns h = htile*128+hhalf*64+lane,
//   k-range = khalf*64 .. +63.
// Weights: 16 f32x4 (64 VGPR) pinned via inline-asm loads (fits the 128-VGPR
// cap at 4 waves/SIMD). x half-row: 4x s_load_dwordx16 into SGPRs (SMEM pipe,
// zero VALU/VMEM cost), consumed as the SGPR operand of v_fmac. Cross-k-half
// reduce via 2-slot LDS parity, one barrier/t (R1-proven). LIF+ballot on kh0.
// ---------------------------------------------------------------------------
__global__ __launch_bounds__(256, 4) void snn_phaseA(
    const float* __restrict__ x, const float* __restrict__ W1,
    const float* __restrict__ b1, uint64_t* __restrict__ s1bits)
{
    const int b = blockIdx.x >> 3;
    const int htile = blockIdx.x & 7;
    const int wv = threadIdx.x >> 6;
    const int lane = threadIdx.x & 63;
    const int kh = __builtin_amdgcn_readfirstlane(wv >> 1);   // 0/1
    const int hhalf = __builtin_amdgcn_readfirstlane(wv & 1); // 0/1
    const int hl = hhalf * 64 + lane;     // 0..127 within tile
    const int h = htile * 128 + hl;

    f32x4 w[16];
    const float* wp = W1 + (size_t)h * NI + kh * 64;
    WL(0, 0);    WL(1, 16);   WL(2, 32);   WL(3, 48);
    WL(4, 64);   WL(5, 80);   WL(6, 96);   WL(7, 112);
    WL(8, 128);  WL(9, 144);  WL(10, 160); WL(11, 176);
    WL(12, 192); WL(13, 208); WL(14, 224); WL(15, 240);
    asm volatile("s_waitcnt vmcnt(0)"
                 : "+v"(w[0]), "+v"(w[1]), "+v"(w[2]), "+v"(w[3]),
                   "+v"(w[4]), "+v"(w[5]), "+v"(w[6]), "+v"(w[7]),
                   "+v"(w[8]), "+v"(w[9]), "+v"(w[10]), "+v"(w[11]),
                   "+v"(w[12]), "+v"(w[13]), "+v"(w[14]), "+v"(w[15])
                 :
                 : "memory");
    __builtin_amdgcn_sched_barrier(0);

    const float bias = b1[h];
    __shared__ float red[2][128];

    const float* __restrict__ xb = x + (size_t)b * NT * NI + kh * 64;
    uint64_t* s1w = s1bits + (size_t)b * (NH / 64) + htile * 2 + hhalf;

    float v = 0.0f;
#pragma unroll 1
    for (int t = 0; t < NT; ++t) {
        const float* xr = xb + (size_t)t * NI;  // wave-uniform -> SGPR pair
        f32x16 x0, x1, x2, x3;
        asm volatile("s_load_dwordx16 %0, %1, 0x0"  : "=s"(x0) : "s"(xr));
        asm volatile("s_load_dwordx16 %0, %1, 0x40" : "=s"(x1) : "s"(xr));
        asm volatile("s_load_dwordx16 %0, %1, 0x80" : "=s"(x2) : "s"(xr));
        asm volatile("s_load_dwordx16 %0, %1, 0xc0" : "=s"(x3) : "s"(xr));
        asm volatile("s_waitcnt lgkmcnt(0)"
                     : "+s"(x0), "+s"(x1), "+s"(x2), "+s"(x3));
        __builtin_amdgcn_sched_barrier(0);

        float a0 = 0.f, a1 = 0.f, a2 = 0.f, a3 = 0.f;
        XF4(x0, 0);
        XF4(x1, 4);
        XF4(x2, 8);
        XF4(x3, 12);
        const float partial = (a0 + a1) + (a2 + a3);

        if (kh) red[t & 1][hl] = partial;
        __syncthreads();
        if (!kh) {
            const float h1 = partial + red[t & 1][hl] + bias;
            v = fmaf(h1 - v, 0.5f, v);  // v += (h1 - v)/tau, tau = 2
            const bool sp = (v >= 1.0f);
            v = sp ? 0.0f : v;
            const unsigned long long m = __ballot(sp);
            if (lane == 0) *s1w = (uint64_t)m;
        }
        s1w += NB * (NH / 64);
        // red[t&1] is re-written at t+2, after barrier(t+1): safe (R1-proven).
    }
}

// ---------------------------------------------------------------------------
// Phase B: sparse GEMM2. One wave per m = t*128+b row; lane covers o = lane
// and o+64. Scalar ff1 loop over 16 mask words; per active k one coalesced
// dwordx2 of W2P[k]. Sparse sum (ascending k) == dense sum exactly.
// ---------------------------------------------------------------------------
__global__ __launch_bounds__(256, 4) void snn_phaseB(
    const uint64_t* __restrict__ s1bits, const float2* __restrict__ W2P,
    float* __restrict__ h2)
{
    const int wv = threadIdx.x >> 6;
    const int lane = threadIdx.x & 63;
    const size_t m = (size_t)blockIdx.x * 4 + wv;  // 0..262143

    const uint64_t* __restrict__ sb = s1bits + m * (NH / 64);
    float a0 = 0.f, a1 = 0.f;

#pragma unroll 1
    for (int wd = 0; wd < NH / 64; ++wd) {
        const uint64_t m64 = sb[wd];
        const uint32_t mlo = (uint32_t)__builtin_amdgcn_readfirstlane((int)(uint32_t)m64);
        const uint32_t mhi = (uint32_t)__builtin_amdgcn_readfirstlane((int)(uint32_t)(m64 >> 32));
        uint64_t msk = ((uint64_t)mhi << 32) | mlo;
        while (msk) {
            const int i = __builtin_ctzll(msk);
            msk &= (msk - 1);
            const size_t k = ((size_t)wd << 6) + i;
            const float2 ww = W2P[k * 64 + lane];
            a0 += ww.x;
            a1 += ww.y;
        }
    }
    h2[m * NO + lane] = a0;
    h2[m * NO + 64 + lane] = a1;
}

// ---------------------------------------------------------------------------
// Phase D: LIF2 scan + decision-window count. 256 blocks of 64 threads,
// unroll 16 for deep load pipelining; lanes <-> consecutive o (coalesced).
// ---------------------------------------------------------------------------
__global__ __launch_bounds__(64) void snn_phaseD(
    const float* __restrict__ h2, const float* __restrict__ b2,
    float* __restrict__ out)
{
    const int idx = blockIdx.x * 64 + threadIdx.x;  // 0..16383
    const int b = idx >> 7;
    const int o = idx & 127;
    const float bias = b2[o];

    const float* __restrict__ p = h2 + (size_t)b * NO + o;
    float v = 0.f, c = 0.f;
#pragma unroll 16
    for (int t = 0; t < NT; ++t) {
        const float hh = p[(size_t)t * NB * NO] + bias;
        v = fmaf(hh - v, 0.5f, v);
        const bool s = (v >= 1.0f);
        v = s ? 0.f : v;
        if (t >= NT / 2) c += s ? 1.f : 0.f;
    }
    out[idx] = c;
}

extern "C" void kernel_launch(void* const* d_in, const int* in_sizes, int n_in,
                              void* d_out, int out_size, void* d_ws,
                              size_t ws_size, hipStream_t stream)
{
    const float* x  = (const float*)d_in[0];
    const float* W1 = (const float*)d_in[1];
    const float* b1 = (const float*)d_in[2];
    const float* W2 = (const float*)d_in[3];
    const float* b2 = (const float*)d_in[4];
    float* out = (float*)d_out;

    // ws layout: [s1bits 33.55 MB][W2P 0.52 MB][h2 134.2 MB]
    uint8_t* ws = (uint8_t*)d_ws;
    uint64_t* s1bits = (uint64_t*)ws;
    float2* W2P = (float2*)(ws + (size_t)NT * NB * (NH / 64) * 8);
    float* h2 = (float*)(ws + (size_t)NT * NB * (NH / 64) * 8 +
                         (size_t)NH * 64 * sizeof(float2));

    w2p_kernel<<<dim3((NH * 64) / 256), dim3(256), 0, stream>>>(W2, W2P);
    snn_phaseA<<<dim3(NB * 8), dim3(256), 0, stream>>>(x, W1, b1, s1bits);
    snn_phaseB<<<dim3((NT * NB) / 4), dim3(256), 0, stream>>>(s1bits, W2P, h2);
    snn_phaseD<<<dim3(256), dim3(64), 0, stream>>>(h2, b2, out);
}